// Round 7
// baseline (795.992 us; speedup 1.0000x reference)
//
#include <hip/hip_runtime.h>
#include <hip/hip_bf16.h>
#include <math.h>

namespace {

constexpr int SEQ    = 64;
constexpr int DINNER = 1024;
constexpr int DFF    = 16;
constexpr int DTRANK = 32;

typedef __attribute__((ext_vector_type(8))) short short8;
typedef __attribute__((ext_vector_type(4))) float f32x4;
typedef __attribute__((address_space(3))) unsigned int lds_u32_t;
typedef __attribute__((address_space(1))) unsigned int glb_u32_t;

__device__ __forceinline__ float sigm(float x) { return 1.f / (1.f + __expf(-x)); }
__device__ __forceinline__ short f2b(float v) {
    __hip_bfloat16 h = __float2bfloat16(v);
    return *(short*)&h;
}
__device__ __forceinline__ float b2f(short s) {
    union { unsigned u; float f; } c; c.u = ((unsigned)(unsigned short)s) << 16; return c.f;
}
__device__ __forceinline__ float softp(float v) {
    return fmaxf(v, 0.f) + log1pf(__expf(-fabsf(v)));
}

// ====== bf16 MFMA GEMM core, 2-phase pipelined (T3 minimum) ======
// BM=128 x BN, BK=32, 4 waves (2x2). As/Bs are DOUBLE buffers:
// As[2*128*32], Bs[2*BN*32]. One barrier per k-step; stage(t+1) issued
// after the barrier overlaps with ds_read+MFMA of tile t.
template <int BN>
__device__ __forceinline__ void gemm_core(
    f32x4 (&acc)[4][BN / 32],
    const short* __restrict__ A, int lda,
    const short* __restrict__ W, int ldw,
    int Kd, short* As, short* Bs, int m0, int n0)
{
    constexpr int NFR = BN / 32;
    constexpr int ASZ = 128 * 32;
    constexpr int BSZ = BN * 32;
    const int tid = threadIdx.x, wave = tid >> 6, lane = tid & 63;
    const int wm = wave >> 1, wn = wave & 1;
    const int l15 = lane & 15, kg = lane >> 4;

    const int pA0 = wave * 128 + lane, pA1 = pA0 + 64;
    const short* srcA0 = A + (size_t)(m0 + (pA0 >> 2)) * lda + (pA0 & 3) * 8;
    const short* srcA1 = A + (size_t)(m0 + (pA1 >> 2)) * lda + (pA1 & 3) * 8;
    const int oA0 = (wave * 128) * 8, oA1 = (wave * 128 + 64) * 8;   // wave-uniform LDS bases

    const short* srcB0; const short* srcB1 = nullptr;
    int oB0 = 0, oB1 = 0;
    if constexpr (BN == 128) {
        const int pB0 = wave * 128 + lane, pB1 = pB0 + 64;
        srcB0 = W + (size_t)(n0 + (pB0 >> 2)) * ldw + (pB0 & 3) * 8;
        srcB1 = W + (size_t)(n0 + (pB1 >> 2)) * ldw + (pB1 & 3) * 8;
        oB0 = (wave * 128) * 8; oB1 = (wave * 128 + 64) * 8;
    } else {
        const int pB0 = wave * 64 + lane;
        srcB0 = W + (size_t)(n0 + (pB0 >> 2)) * ldw + (pB0 & 3) * 8;
        oB0 = (wave * 64) * 8;
    }

    const int nt = Kd >> 5;
    // prologue: stage tile 0 into buffer 0
    __builtin_amdgcn_global_load_lds((const glb_u32_t*)srcA0, (lds_u32_t*)(As + oA0), 16, 0, 0);
    __builtin_amdgcn_global_load_lds((const glb_u32_t*)srcA1, (lds_u32_t*)(As + oA1), 16, 0, 0);
    __builtin_amdgcn_global_load_lds((const glb_u32_t*)srcB0, (lds_u32_t*)(Bs + oB0), 16, 0, 0);
    if constexpr (BN == 128)
        __builtin_amdgcn_global_load_lds((const glb_u32_t*)srcB1, (lds_u32_t*)(Bs + oB1), 16, 0, 0);

    for (int t = 0; t < nt; t++) {
        __syncthreads();   // drains stage for buf[t&1] (and prior iter's ds_reads)
        if (t + 1 < nt) {  // prefetch next tile into other buffer; flies during compute
            const int k0 = (t + 1) * 32;
            const int sa = ((t + 1) & 1) * ASZ, sb = ((t + 1) & 1) * BSZ;
            __builtin_amdgcn_global_load_lds((const glb_u32_t*)(srcA0 + k0), (lds_u32_t*)(As + sa + oA0), 16, 0, 0);
            __builtin_amdgcn_global_load_lds((const glb_u32_t*)(srcA1 + k0), (lds_u32_t*)(As + sa + oA1), 16, 0, 0);
            __builtin_amdgcn_global_load_lds((const glb_u32_t*)(srcB0 + k0), (lds_u32_t*)(Bs + sb + oB0), 16, 0, 0);
            if constexpr (BN == 128)
                __builtin_amdgcn_global_load_lds((const glb_u32_t*)(srcB1 + k0), (lds_u32_t*)(Bs + sb + oB1), 16, 0, 0);
        }
        const short* Ab = As + (t & 1) * ASZ;
        const short* Bb = Bs + (t & 1) * BSZ;
        short8 af[4], bfr[NFR];
#pragma unroll
        for (int mi = 0; mi < 4; mi++)
            af[mi] = *(const short8*)(Ab + (wm * 64 + mi * 16 + l15) * 32 + kg * 8);
#pragma unroll
        for (int ni = 0; ni < NFR; ni++)
            bfr[ni] = *(const short8*)(Bb + (wn * (BN / 2) + ni * 16 + l15) * 32 + kg * 8);
#pragma unroll
        for (int mi = 0; mi < 4; mi++)
#pragma unroll
            for (int ni = 0; ni < NFR; ni++)
                acc[mi][ni] = __builtin_amdgcn_mfma_f32_16x16x32_bf16(af[mi], bfr[ni], acc[mi][ni], 0, 0, 0);
    }
}
// C/D frag mapping [m89]: col = n0 + wn*(BN/2) + ni*16 + (lane&15);
//                         row = m0 + wm*64 + mi*16 + (lane>>4)*4 + j

// ================= prep: conversions (+gamma fold), W_delta, zeroing =================
__global__ __launch_bounds__(256) void prep_k(
    const float* __restrict__ lin1_w, const float* __restrict__ gate_w,
    const float* __restrict__ lin2_w, const float* __restrict__ in_proj_w,
    const float* __restrict__ out_proj_w, const float* __restrict__ proj_w,
    const float* __restrict__ x_proj_w, const float* __restrict__ dt_proj_w,
    const float* __restrict__ inputs, const float* __restrict__ blk_norm_w,
    const float* __restrict__ post_norm_w,
    short* __restrict__ wlin1gb, short* __restrict__ wlin2b, short* __restrict__ winpb,
    short* __restrict__ woutpb, short* __restrict__ wprojb, short* __restrict__ wxpdb,
    short* __restrict__ inputsb, float* __restrict__ preds, float* __restrict__ ss)
{
    const int blk = blockIdx.x, tid = threadIdx.x;
    if (blk < 1024) {
        // W_delta = dt_w(1024x32) @ xp_w[:32](32x1024), per layer; wave per n-row
        const int wave = tid >> 6, lane = tid & 63;
        const int nrow = blk * 4 + wave;          // 0..4095
        const int l = nrow >> 10, n = nrow & 1023;
        const float* dtw = dt_proj_w + (size_t)l * 32768 + n * 32;
        const float* xpw = x_proj_w + (size_t)l * 65536;
        float4 acc[4] = {};
        for (int r = 0; r < 32; r++) {
            const float s = dtw[r];
#pragma unroll
            for (int rep = 0; rep < 4; rep++) {
                const float4 xv = *(const float4*)(xpw + r * 1024 + rep * 256 + lane * 4);
                acc[rep].x = fmaf(s, xv.x, acc[rep].x);
                acc[rep].y = fmaf(s, xv.y, acc[rep].y);
                acc[rep].z = fmaf(s, xv.z, acc[rep].z);
                acc[rep].w = fmaf(s, xv.w, acc[rep].w);
            }
        }
        short* dst = wxpdb + (size_t)l * 1114112 + (size_t)(64 + n) * 1024;
#pragma unroll
        for (int rep = 0; rep < 4; rep++) {
            union { short sh[4]; uint2 u; } pk;
            pk.sh[0] = f2b(acc[rep].x); pk.sh[1] = f2b(acc[rep].y);
            pk.sh[2] = f2b(acc[rep].z); pk.sh[3] = f2b(acc[rep].w);
            *(uint2*)(dst + rep * 256 + lane * 4) = pk.u;
        }
    } else if (blk < 1088) {
#pragma unroll
        for (int rep = 0; rep < 4; rep++) {
            const int e = (blk - 1024) * 4096 + rep * 1024 + tid * 4;  // < 262144
            const int l = e >> 16, rowk = e & 65535;
            const float4 v = *(const float4*)(x_proj_w + (size_t)l * 65536 + rowk);
            union { short sh[4]; uint2 u; } pk;
            pk.sh[0] = f2b(v.x); pk.sh[1] = f2b(v.y); pk.sh[2] = f2b(v.z); pk.sh[3] = f2b(v.w);
            *(uint2*)(wxpdb + (size_t)l * 1114112 + rowk) = pk.u;
        }
    } else if (blk < 2048) {
        constexpr int pre[8] = {0, 128, 256, 512, 4608, 6656, 7680, 7936};
        for (int vb = blk - 1088; vb < 7936; vb += 960) {
            int s = 0;
#pragma unroll
            for (int i = 1; i < 7; i++) s += (vb >= pre[i]);
            const int e = (vb - pre[s]) * 1024 + tid * 4;
            const float* src; short* dst;
            bool hasG = false; const float* gp = nullptr;
            if      (s == 0) { src = lin1_w + e;     dst = wlin1gb + e; }
            else if (s == 1) { src = gate_w + e;     dst = wlin1gb + 131072 + e; }
            else if (s == 2) { src = lin2_w + e;     dst = wlin2b + e; }
            else if (s == 3) { src = in_proj_w + e;  dst = winpb + e;
                               hasG = true; gp = blk_norm_w + (e >> 20) * 512 + (e & 511); }
            else if (s == 4) { src = out_proj_w + e; dst = woutpb + e; }
            else if (s == 5) { src = proj_w + e;     dst = wprojb + e;
                               hasG = true; gp = post_norm_w + (e & 511); }
            else             { src = inputs + e;     dst = inputsb + e; }
            float4 v = *(const float4*)src;
            if (hasG) {
                const float4 gv = *(const float4*)gp;
                v.x *= gv.x; v.y *= gv.y; v.z *= gv.z; v.w *= gv.w;
            }
            union { short sh[4]; uint2 u; } pk;
            pk.sh[0] = f2b(v.x); pk.sh[1] = f2b(v.y); pk.sh[2] = f2b(v.z); pk.sh[3] = f2b(v.w);
            *(uint2*)dst = pk.u;
        }
    } else {
        const int i = (blk - 2048) * 256 + tid;   // < 8192
        if (i < 4096) preds[i] = 0.f;
        else ss[1024 + (i - 4096)] = 0.f;          // zero ss slots 1..4
    }
}

// ================= spatial: lin1|gate merged (N=1024) =================
__global__ __launch_bounds__(256) void lin1gate_k(
    const short* __restrict__ A, const short* __restrict__ W,
    const float* __restrict__ b1, const float* __restrict__ b2,
    short* __restrict__ h1b, float* __restrict__ g)
{
    __shared__ short As[2 * 128 * 32];
    __shared__ short Bs[2 * 128 * 32];
    f32x4 acc[4][4] = {};
    const int m0 = blockIdx.y * 128, n0 = blockIdx.x * 128;
    gemm_core<128>(acc, A, 256, W, 256, 256, As, Bs, m0, n0);
    const int lane = threadIdx.x & 63, wave = threadIdx.x >> 6;
    const int wm = wave >> 1, wn = wave & 1, l15 = lane & 15, kg = lane >> 4;
#pragma unroll
    for (int ni = 0; ni < 4; ni++) {
        const int col = n0 + wn * 64 + ni * 16 + l15;
        const bool isG = col >= 512;
        const float b = isG ? b2[col - 512] : b1[col];
#pragma unroll
        for (int mi = 0; mi < 4; mi++)
#pragma unroll
            for (int j = 0; j < 4; j++) {
                const int row = m0 + wm * 64 + mi * 16 + kg * 4 + j;
                const float v = acc[mi][ni][j] + b;
                if (isG) g[(size_t)row * 512 + (col - 512)] = sigm(v);
                else     h1b[(size_t)row * 512 + col] = f2b(0.5f * v * (1.f + erff(v * 0.70710678f)));
            }
    }
}

// ================= lin2: x = (h1 @ W^T + b) * g =================
__global__ __launch_bounds__(256) void lin2_k(
    const short* __restrict__ A, const short* __restrict__ W,
    const float* __restrict__ bias, const float* __restrict__ g, float* __restrict__ x)
{
    __shared__ short As[2 * 128 * 32];
    __shared__ short Bs[2 * 128 * 32];
    f32x4 acc[4][4] = {};
    const int m0 = blockIdx.y * 128, n0 = blockIdx.x * 128;
    gemm_core<128>(acc, A, 512, W, 512, 512, As, Bs, m0, n0);
    const int lane = threadIdx.x & 63, wave = threadIdx.x >> 6;
    const int wm = wave >> 1, wn = wave & 1, l15 = lane & 15, kg = lane >> 4;
#pragma unroll
    for (int ni = 0; ni < 4; ni++) {
        const int col = n0 + wn * 64 + ni * 16 + l15;
        const float b = bias[col];
#pragma unroll
        for (int mi = 0; mi < 4; mi++)
#pragma unroll
            for (int j = 0; j < 4; j++) {
                const int row = m0 + wm * 64 + mi * 16 + kg * 4 + j;
                x[(size_t)row * 512 + col] = (acc[mi][ni][j] + b) * g[(size_t)row * 512 + col];
            }
    }
}

// ================= spatial rmsnorm: h fp32 + hb bf16 + ss[0] =================
__global__ __launch_bounds__(256) void rms_sp_k(
    const float* __restrict__ x, const float* __restrict__ w,
    float* __restrict__ h, short* __restrict__ hb, float* __restrict__ ss0)
{
    const int lane = threadIdx.x & 63;
    const int rowId = blockIdx.x * 4 + (threadIdx.x >> 6);
    const float* ip = x + (size_t)rowId * 512 + lane * 8;
    const float4 v1 = *(const float4*)ip;
    const float4 v2 = *(const float4*)(ip + 4);
    float sq = v1.x * v1.x + v1.y * v1.y + v1.z * v1.z + v1.w * v1.w
             + v2.x * v2.x + v2.y * v2.y + v2.z * v2.z + v2.w * v2.w;
#pragma unroll
    for (int off = 32; off > 0; off >>= 1) sq += __shfl_xor(sq, off, 64);
    const float rs = rsqrtf(sq * (1.f / 512.f) + 1e-5f);
    const float4 w1 = *(const float4*)(w + lane * 8);
    const float4 w2 = *(const float4*)(w + lane * 8 + 4);
    const float o[8] = { v1.x * rs * w1.x, v1.y * rs * w1.y, v1.z * rs * w1.z, v1.w * rs * w1.w,
                         v2.x * rs * w2.x, v2.y * rs * w2.y, v2.z * rs * w2.z, v2.w * rs * w2.w };
    float* op = h + (size_t)rowId * 512 + lane * 8;
    *(float4*)op       = make_float4(o[0], o[1], o[2], o[3]);
    *(float4*)(op + 4) = make_float4(o[4], o[5], o[6], o[7]);
    short8 pk;
#pragma unroll
    for (int i = 0; i < 8; i++) pk[i] = f2b(o[i]);
    *(short8*)(hb + (size_t)rowId * 512 + lane * 8) = pk;
    float s2 = 0.f;
#pragma unroll
    for (int i = 0; i < 8; i++) s2 = fmaf(o[i], o[i], s2);
#pragma unroll
    for (int off = 32; off > 0; off >>= 1) s2 += __shfl_xor(s2, off, 64);
    if (lane == 0) ss0[rowId] = s2;
}

// ================= in_proj + fused depthwise conv + silu =================
// Tile 128 rows (2 whole batches) x 128 cols. n0<1024: conv cols; n0>=1024: silu(res) bf16.
union ConvU {
    struct { short As[2 * 128 * 32]; short Bs[2 * 128 * 32]; } gm;   // 32 KB (GEMM)
    float cbuf[67][132];                                              // 35.4 KB (conv)
};

__global__ __launch_bounds__(256) void inprojconv_k(
    const short* __restrict__ A, const short* __restrict__ W,
    const float* __restrict__ ss_in, const float* __restrict__ cw,
    const float* __restrict__ cb, short* __restrict__ xcb, short* __restrict__ srb)
{
    __shared__ ConvU u;
    f32x4 acc[4][4] = {};
    const int m0 = blockIdx.y * 128, n0 = blockIdx.x * 128;
    gemm_core<128>(acc, A, 512, W, 512, 512, u.gm.As, u.gm.Bs, m0, n0);
    const int tid = threadIdx.x;
    const int lane = tid & 63, wave = tid >> 6;
    const int wm = wave >> 1, wn = wave & 1, l15 = lane & 15, kg = lane >> 4;

    // rmsnorm row scale
#pragma unroll
    for (int mi = 0; mi < 4; mi++)
#pragma unroll
        for (int j = 0; j < 4; j++) {
            const int row = m0 + wm * 64 + mi * 16 + kg * 4 + j;
            const float r = rsqrtf(ss_in[row] * (1.f / 512.f) + 1e-5f);
#pragma unroll
            for (int ni = 0; ni < 4; ni++) acc[mi][ni][j] *= r;
        }

    if (n0 < 1024) {
        // ---- two-pass LDS conv over the tile (causal within each 64-row batch) ----
        const int ccol = tid & 127;        // fixed col per thread
        const int r0 = tid >> 7;           // 0/1
        const int d = n0 + ccol;
        const float4 w4 = *(const float4*)(cw + d * 4);
        const float bia = cb[d];

        __syncthreads();   // all waves done with As/Bs LDS (gemm ds_reads drained)
        // pass 1: rows 0..63 (wm==0 waves) into slots 3..66; zero-pad slots 0..2
        if (wm == 0)
#pragma unroll
            for (int mi = 0; mi < 4; mi++)
#pragma unroll
                for (int ni = 0; ni < 4; ni++)
#pragma unroll
                    for (int j = 0; j < 4; j++)
                        u.cbuf[3 + mi * 16 + kg * 4 + j][wn * 64 + ni * 16 + l15] = acc[mi][ni][j];
        for (int i = tid; i < 384; i += 256) u.cbuf[i >> 7][i & 127] = 0.f;
        __syncthreads();
#pragma unroll 4
        for (int k = 0; k < 32; k++) {
            const int row = r0 + 2 * k;    // 0..63
            float v = bia + w4.x * u.cbuf[row][ccol] + w4.y * u.cbuf[row + 1][ccol]
                          + w4.z * u.cbuf[row + 2][ccol] + w4.w * u.cbuf[row + 3][ccol];
            v = v * sigm(v);
            xcb[(size_t)(m0 + row) * 1024 + d] = f2b(v);
        }
        __syncthreads();
        // carry rows 61..63 (slots 64..66) into pad slots 0..2
        for (int i = tid; i < 384; i += 256) u.cbuf[i >> 7][i & 127] = u.cbuf[64 + (i >> 7)][i & 127];
        __syncthreads();
        // pass 2: rows 64..127 (wm==1 waves)
        if (wm == 1)
#pragma unroll
            for (int mi = 0; mi < 4; mi++)
#pragma unroll
                for (int ni = 0; ni < 4; ni++)
#pragma unroll
                    for (int j = 0; j < 4; j++)
                        u.cbuf[3 + mi * 16 + kg * 4 + j][wn * 64 + ni * 16 + l15] = acc[mi][ni][j];
        __syncthreads();
#pragma unroll 4
        for (int k = 0; k < 32; k++) {
            const int row = r0 + 2 * k;    // local 0..63 -> global m0+64+row
            float v = bia + w4.x * u.cbuf[row][ccol] + w4.y * u.cbuf[row + 1][ccol]
                          + w4.z * u.cbuf[row + 2][ccol] + w4.w * u.cbuf[row + 3][ccol];
            v = v * sigm(v);
            xcb[(size_t)(m0 + 64 + row) * 1024 + d] = f2b(v);
        }
    } else {
        // res half: store silu(res) as bf16
#pragma unroll
        for (int ni = 0; ni < 4; ni++) {
            const int scol = n0 - 1024 + wn * 64 + ni * 16 + l15;
#pragma unroll
            for (int mi = 0; mi < 4; mi++)
#pragma unroll
                for (int j = 0; j < 4; j++) {
                    const int row = m0 + wm * 64 + mi * 16 + kg * 4 + j;
                    const float v = acc[mi][ni][j];
                    srb[(size_t)row * 1024 + scol] = f2b(v * sigm(v));
                }
        }
    }
}

// ================= xpd: [xdbl | delta] = xcb @ [xpw; W_delta]^T (N=1088) =================
__global__ __launch_bounds__(256) void xpd_k(
    const short* __restrict__ A, const short* __restrict__ W,
    const float* __restrict__ dtb, float* __restrict__ xdbl, float* __restrict__ delta)
{
    __shared__ short As[2 * 128 * 32];
    __shared__ short Bs[2 * 64 * 32];
    f32x4 acc[4][2] = {};
    const int m0 = blockIdx.y * 128, n0 = blockIdx.x * 64;
    gemm_core<64>(acc, A, 1024, W, 1024, 1024, As, Bs, m0, n0);
    const int lane = threadIdx.x & 63, wave = threadIdx.x >> 6;
    const int wm = wave >> 1, wn = wave & 1, l15 = lane & 15, kg = lane >> 4;
#pragma unroll
    for (int ni = 0; ni < 2; ni++) {
        const int col = n0 + wn * 32 + ni * 16 + l15;
#pragma unroll
        for (int mi = 0; mi < 4; mi++)
#pragma unroll
            for (int j = 0; j < 4; j++) {
                const int row = m0 + wm * 64 + mi * 16 + kg * 4 + j;
                const float v = acc[mi][ni][j];
                if (col < 64) xdbl[(size_t)row * 64 + col] = v;
                else          delta[(size_t)row * 1024 + (col - 64)] = softp(v + dtb[col - 64]);
            }
    }
}

// ================= scan: 256 blocks x 64 thr; u and silu(res) from bf16 ====
__global__ __launch_bounds__(64) void scan_k(
    const short* __restrict__ xcb, const float* __restrict__ delta,
    const float* __restrict__ xdbl, const float* __restrict__ Alog,
    const float* __restrict__ Dp, const short* __restrict__ srb, short* __restrict__ yb)
{
    const int b = blockIdx.x >> 4;
    const int d = ((blockIdx.x & 15) << 6) + threadIdx.x;
    __shared__ float Bsh[SEQ][DFF];
    __shared__ float Csh[SEQ][DFF];
    for (int i = threadIdx.x; i < SEQ * DFF; i += 64) {
        const int l = i >> 4, n = i & 15;
        Bsh[l][n] = xdbl[(size_t)(b * SEQ + l) * 64 + DTRANK + n];
        Csh[l][n] = xdbl[(size_t)(b * SEQ + l) * 64 + DTRANK + DFF + n];
    }
    __syncthreads();
    float a[16], s[16];
#pragma unroll
    for (int n = 0; n < 16; n++) { a[n] = -__expf(Alog[(size_t)d * 16 + n]); s[n] = 0.f; }
    const float dv = Dp[d];
    for (int l = 0; l < SEQ; l++) {
        const size_t m = (size_t)b * SEQ + l;
        const float dlt = delta[m * DINNER + d];
        const float uu = b2f(xcb[m * DINNER + d]);
        const float dbu = dlt * uu;
        float acc = 0.f;
#pragma unroll
        for (int n = 0; n < 16; n++) {
            s[n] = __expf(dlt * a[n]) * s[n] + dbu * Bsh[l][n];
            acc = fmaf(s[n], Csh[l][n], acc);
        }
        acc = fmaf(uu, dv, acc);
        yb[m * DINNER + d] = f2b(acc * b2f(srb[m * 1024 + d]));
    }
}

// ================= out_proj: h += yb @ W^T; writes h fp32 + hb bf16 + ss_out =========
__global__ __launch_bounds__(256) void outproj_k(
    const short* __restrict__ A, const short* __restrict__ W,
    float* __restrict__ h, short* __restrict__ hb, float* __restrict__ ss_out)
{
    __shared__ short As[2 * 128 * 32];
    __shared__ short Bs[2 * 128 * 32];
    f32x4 acc[4][4] = {};
    const int m0 = blockIdx.y * 128, n0 = blockIdx.x * 128;
    gemm_core<128>(acc, A, 1024, W, 1024, 1024, As, Bs, m0, n0);
    const int lane = threadIdx.x & 63, wave = threadIdx.x >> 6;
    const int wm = wave >> 1, wn = wave & 1, l15 = lane & 15, kg = lane >> 4;
    float vsq[4][4] = {};
#pragma unroll
    for (int ni = 0; ni < 4; ni++) {
        const int col = n0 + wn * 64 + ni * 16 + l15;
#pragma unroll
        for (int mi = 0; mi < 4; mi++)
#pragma unroll
            for (int j = 0; j < 4; j++) {
                const int row = m0 + wm * 64 + mi * 16 + kg * 4 + j;
                const float v = acc[mi][ni][j] + h[(size_t)row * 512 + col];
                h[(size_t)row * 512 + col] = v;
                hb[(size_t)row * 512 + col] = f2b(v);
                vsq[mi][j] = fmaf(v, v, vsq[mi][j]);
            }
    }
#pragma unroll
    for (int mi = 0; mi < 4; mi++)
#pragma unroll
        for (int j = 0; j < 4; j++) {
            float t = vsq[mi][j];
            t += __shfl_xor(t, 1, 64);
            t += __shfl_xor(t, 2, 64);
            t += __shfl_xor(t, 4, 64);
            t += __shfl_xor(t, 8, 64);
            if (l15 == 0) {
                const int row = m0 + wm * 64 + mi * 16 + kg * 4 + j;
                atomicAdd(ss_out + row, t);
            }
        }
}

// ================= final proj: xr = r[row] * (hb @ (W.gamma)^T) =================
__global__ __launch_bounds__(256) void projf_k(
    const short* __restrict__ A, const short* __restrict__ W,
    const float* __restrict__ ss_in, float* __restrict__ xr)
{
    __shared__ short As[2 * 128 * 32];
    __shared__ short Bs[2 * 128 * 32];
    f32x4 acc[4][4] = {};
    const int m0 = blockIdx.y * 128, n0 = blockIdx.x * 128;
    gemm_core<128>(acc, A, 512, W, 512, 512, As, Bs, m0, n0);
    const int lane = threadIdx.x & 63, wave = threadIdx.x >> 6;
    const int wm = wave >> 1, wn = wave & 1, l15 = lane & 15, kg = lane >> 4;
#pragma unroll
    for (int mi = 0; mi < 4; mi++)
#pragma unroll
        for (int j = 0; j < 4; j++) {
            const int row = m0 + wm * 64 + mi * 16 + kg * 4 + j;
            const float r = rsqrtf(ss_in[row] * (1.f / 512.f) + 1e-5f);
#pragma unroll
            for (int ni = 0; ni < 4; ni++) {
                const int col = n0 + wn * 64 + ni * 16 + l15;
                xr[(size_t)row * 2048 + col] = acc[mi][ni][j] * r;
            }
        }
}

// ================= coeffs + preds =================
__global__ __launch_bounds__(256) void coeffs_k(
    const float* __restrict__ outp, const float* __restrict__ inp,
    float* __restrict__ coeffs, float* __restrict__ preds)
{
    const int m = blockIdx.x;
    const int b = m >> 6;
    const int tid = threadIdx.x, wave = tid >> 6, lane = tid & 63;
    __shared__ float4 Us[256], Vs[256];
    __shared__ float ins[256];
    __shared__ float4 tpart[4];
    Us[tid] = *(const float4*)(outp + (size_t)m * 2048 + tid * 4);
    Vs[tid] = *(const float4*)(outp + (size_t)m * 2048 + 1024 + tid * 4);
    ins[tid] = inp[(size_t)m * 256 + tid];
    __syncthreads();
    const float4 vq0 = Vs[lane * 4 + 0], vq1 = Vs[lane * 4 + 1];
    const float4 vq2 = Vs[lane * 4 + 2], vq3 = Vs[lane * 4 + 3];
    float* cbase = coeffs + (size_t)m * 65536 + lane * 4;
#pragma unroll 4
    for (int i = 0; i < 64; i++) {
        const int pp = (wave << 6) + i;
        const float4 up = Us[pp];
        float4 c;
        c.x = up.x * vq0.x + up.y * vq0.y + up.z * vq0.z + up.w * vq0.w;
        c.y = up.x * vq1.x + up.y * vq1.y + up.z * vq1.z + up.w * vq1.w;
        c.z = up.x * vq2.x + up.y * vq2.y + up.z * vq2.z + up.w * vq2.w;
        c.w = up.x * vq3.x + up.y * vq3.y + up.z * vq3.z + up.w * vq3.w;
        *(float4*)(cbase + (size_t)pp * 256) = c;
    }
    const float iv = ins[tid];
    const float4 vm = Vs[tid];
    float4 t = make_float4(vm.x * iv, vm.y * iv, vm.z * iv, vm.w * iv);
#pragma unroll
    for (int off = 32; off > 0; off >>= 1) {
        t.x += __shfl_xor(t.x, off, 64);
        t.y += __shfl_xor(t.y, off, 64);
        t.z += __shfl_xor(t.z, off, 64);
        t.w += __shfl_xor(t.w, off, 64);
    }
    if (lane == 0) tpart[wave] = t;
    __syncthreads();
    const float4 t0 = tpart[0], t1 = tpart[1], t2 = tpart[2], t3 = tpart[3];
    const float4 tt = make_float4(t0.x + t1.x + t2.x + t3.x, t0.y + t1.y + t2.y + t3.y,
                                  t0.z + t1.z + t2.z + t3.z, t0.w + t1.w + t2.w + t3.w);
    const float4 up = Us[tid];
    const float pv = up.x * tt.x + up.y * tt.y + up.z * tt.z + up.w * tt.w;
    atomicAdd(preds + (size_t)b * 256 + tid, pv);
}

} // namespace

extern "C" void kernel_launch(void* const* d_in, const int* in_sizes, int n_in,
                              void* d_out, int out_size, void* d_ws, size_t ws_size,
                              hipStream_t stream)
{
    const float* inputs     = (const float*)d_in[0];
    const float* lin1_w     = (const float*)d_in[1];
    const float* lin1_b     = (const float*)d_in[2];
    const float* lin2_w     = (const float*)d_in[3];
    const float* lin2_b     = (const float*)d_in[4];
    const float* gate_w     = (const float*)d_in[5];
    const float* gate_b     = (const float*)d_in[6];
    const float* sp_norm_w  = (const float*)d_in[7];
    const float* in_proj_w  = (const float*)d_in[8];
    const float* conv_w     = (const float*)d_in[9];
    const float* conv_b     = (const float*)d_in[10];
    const float* x_proj_w   = (const float*)d_in[11];
    const float* dt_proj_w  = (const float*)d_in[12];
    const float* dt_proj_b  = (const float*)d_in[13];
    const float* A_log      = (const float*)d_in[14];
    const float* Dvec       = (const float*)d_in[15];
    const float* out_proj_w = (const float*)d_in[16];
    const float* blk_norm_w = (const float*)d_in[17];
    const float* post_norm_w= (const float*)d_in[18];
    const float* proj_w     = (const float*)d_in[19];

    float* ws = (float*)d_ws;
    // fp32 region
    float* h     = ws;                 // 1024 x 512
    float* xr    = ws + 524288;        // 1024 x 2048 (final proj out)
    float* x     = ws + 2621440;       // 1024 x 512 (lin2 out)
    float* g     = ws + 3145728;       // 1024 x 512
    float* delta = ws + 3670016;       // 1024 x 1024
    float* xdbl  = ws + 4718592;       // 1024 x 64
    float* ss    = ws + 4784128;       // 5 x 1024 sumsq slots
    // bf16 region
    short* bfb     = (short*)(ws + 4790272);
    short* inputsb = bfb;               // 1024 x 256
    short* h1b     = bfb + 262144;      // 1024 x 512
    short* hb      = bfb + 786432;      // 1024 x 512
    short* xcb     = bfb + 1310720;     // 1024 x 1024
    short* yb      = bfb + 2359296;     // 1024 x 1024
    short* srb     = bfb + 3407872;     // 1024 x 1024 silu(res)
    short* wlin1gb = bfb + 4456448;     // 1024 x 256
    short* wlin2b  = bfb + 4718592;     // 512 x 512
    short* winpb   = bfb + 4980736;     // 4 x 2048 x 512 (gamma-folded)
    short* woutpb  = bfb + 9175040;     // 4 x 512 x 1024
    short* wprojb  = bfb + 11272192;    // 2048 x 512 (gamma-folded)
    short* wxpdb   = bfb + 12320768;    // 4 x 1088 x 1024 ([xpw; W_delta])
    float* preds  = (float*)d_out;
    float* coeffs = (float*)d_out + 4096;

    const dim3 blk(256);

    prep_k<<<dim3(2080), blk, 0, stream>>>(
        lin1_w, gate_w, lin2_w, in_proj_w, out_proj_w, proj_w, x_proj_w, dt_proj_w,
        inputs, blk_norm_w, post_norm_w,
        wlin1gb, wlin2b, winpb, woutpb, wprojb, wxpdb, inputsb, preds, ss);

    lin1gate_k<<<dim3(8, 8), blk, 0, stream>>>(inputsb, wlin1gb, lin1_b, gate_b, h1b, g);
    lin2_k<<<dim3(4, 8), blk, 0, stream>>>(h1b, wlin2b, lin2_b, g, x);
    rms_sp_k<<<dim3(256), blk, 0, stream>>>(x, sp_norm_w, h, hb, ss);

    for (int l = 0; l < 4; l++) {
        inprojconv_k<<<dim3(16, 8), blk, 0, stream>>>(
            hb, winpb + (size_t)l * 1048576, ss + l * 1024,
            conv_w + (size_t)l * 4096, conv_b + l * 1024, xcb, srb);
        xpd_k<<<dim3(17, 8), blk, 0, stream>>>(xcb, wxpdb + (size_t)l * 1114112,
                                               dt_proj_b + l * 1024, xdbl, delta);
        scan_k<<<dim3(256), dim3(64), 0, stream>>>(xcb, delta, xdbl, A_log + (size_t)l * 16384,
                                                   Dvec + l * 1024, srb, yb);
        outproj_k<<<dim3(4, 8), blk, 0, stream>>>(yb, woutpb + (size_t)l * 524288,
                                                  h, hb, ss + (l + 1) * 1024);
    }

    projf_k<<<dim3(16, 8), blk, 0, stream>>>(hb, wprojb, ss + 4096, xr);
    coeffs_k<<<dim3(1024), blk, 0, stream>>>(xr, inputs, coeffs, preds);
}

// Round 8
// 479.996 us; speedup vs baseline: 1.6583x; 1.6583x over previous
//
#include <hip/hip_runtime.h>
#include <hip/hip_bf16.h>
#include <math.h>

namespace {

constexpr int SEQ    = 64;
constexpr int DINNER = 1024;
constexpr int DFF    = 16;
constexpr int DTRANK = 32;

typedef __attribute__((ext_vector_type(8))) short short8;
typedef __attribute__((ext_vector_type(4))) float f32x4;
typedef __attribute__((address_space(3))) unsigned int lds_u32_t;
typedef __attribute__((address_space(1))) unsigned int glb_u32_t;

__device__ __forceinline__ float sigm(float x) { return 1.f / (1.f + __expf(-x)); }
__device__ __forceinline__ short f2b(float v) {
    __hip_bfloat16 h = __float2bfloat16(v);
    return *(short*)&h;
}
__device__ __forceinline__ float b2f(short s) {
    union { unsigned u; float f; } c; c.u = ((unsigned)(unsigned short)s) << 16; return c.f;
}
__device__ __forceinline__ float softp(float v) {
    return fmaxf(v, 0.f) + log1pf(__expf(-fabsf(v)));
}

// ====== bf16 MFMA GEMM core, 64x64 tile, 2-phase pipelined ======
// 4 waves (2x2), wave tile 32x32, acc[2][2]. As/Bs double buffers (2*64*32 each).
// One barrier per k-step; stage(t+1) overlaps compute(t). High occupancy:
// 16 KB LDS + light VGPR -> 2+ blocks/CU.
__device__ __forceinline__ void gemm_core64(
    f32x4 (&acc)[2][2],
    const short* __restrict__ A, int lda,
    const short* __restrict__ W, int ldw,
    int Kd, short* As, short* Bs, int m0, int n0)
{
    constexpr int SZ = 64 * 32;
    const int tid = threadIdx.x, wave = tid >> 6, lane = tid & 63;
    const int wm = wave >> 1, wn = wave & 1;
    const int l15 = lane & 15, kg = lane >> 4;

    const int p = wave * 64 + lane;   // 16B chunk: row p>>2, slot p&3
    const short* srcA = A + (size_t)(m0 + (p >> 2)) * lda + (p & 3) * 8;
    const short* srcB = W + (size_t)(n0 + (p >> 2)) * ldw + (p & 3) * 8;
    const int ob = (wave * 64) * 8;   // wave-uniform LDS base (shorts)

    const int nt = Kd >> 5;
    __builtin_amdgcn_global_load_lds((const glb_u32_t*)srcA, (lds_u32_t*)(As + ob), 16, 0, 0);
    __builtin_amdgcn_global_load_lds((const glb_u32_t*)srcB, (lds_u32_t*)(Bs + ob), 16, 0, 0);

    for (int t = 0; t < nt; t++) {
        __syncthreads();   // drains stage for buf[t&1] + prior ds_reads
        if (t + 1 < nt) {
            const int k0 = (t + 1) * 32;
            const int s = ((t + 1) & 1) * SZ;
            __builtin_amdgcn_global_load_lds((const glb_u32_t*)(srcA + k0), (lds_u32_t*)(As + s + ob), 16, 0, 0);
            __builtin_amdgcn_global_load_lds((const glb_u32_t*)(srcB + k0), (lds_u32_t*)(Bs + s + ob), 16, 0, 0);
        }
        const short* Ab = As + (t & 1) * SZ;
        const short* Bb = Bs + (t & 1) * SZ;
        short8 af[2], bfr[2];
#pragma unroll
        for (int mi = 0; mi < 2; mi++)
            af[mi] = *(const short8*)(Ab + (wm * 32 + mi * 16 + l15) * 32 + kg * 8);
#pragma unroll
        for (int ni = 0; ni < 2; ni++)
            bfr[ni] = *(const short8*)(Bb + (wn * 32 + ni * 16 + l15) * 32 + kg * 8);
#pragma unroll
        for (int mi = 0; mi < 2; mi++)
#pragma unroll
            for (int ni = 0; ni < 2; ni++)
                acc[mi][ni] = __builtin_amdgcn_mfma_f32_16x16x32_bf16(af[mi], bfr[ni], acc[mi][ni], 0, 0, 0);
    }
}
// C/D frag [m89]: col = n0 + wn*32 + ni*16 + (lane&15);
//                 row = m0 + wm*32 + mi*16 + (lane>>4)*4 + j

// ================= prep: conversions (+gamma fold), W_delta, zeroing =================
__global__ __launch_bounds__(256) void prep_k(
    const float* __restrict__ lin1_w, const float* __restrict__ gate_w,
    const float* __restrict__ lin2_w, const float* __restrict__ in_proj_w,
    const float* __restrict__ out_proj_w, const float* __restrict__ proj_w,
    const float* __restrict__ x_proj_w, const float* __restrict__ dt_proj_w,
    const float* __restrict__ inputs, const float* __restrict__ blk_norm_w,
    const float* __restrict__ post_norm_w,
    short* __restrict__ wlin1gb, short* __restrict__ wlin2b, short* __restrict__ winpb,
    short* __restrict__ woutpb, short* __restrict__ wprojb, short* __restrict__ wxpdb,
    short* __restrict__ inputsb, float* __restrict__ preds, float* __restrict__ ss)
{
    const int blk = blockIdx.x, tid = threadIdx.x;
    if (blk < 1024) {
        // W_delta = dt_w(1024x32) @ xp_w[:32](32x1024), per layer; wave per n-row
        const int wave = tid >> 6, lane = tid & 63;
        const int nrow = blk * 4 + wave;          // 0..4095
        const int l = nrow >> 10, n = nrow & 1023;
        const float* dtw = dt_proj_w + (size_t)l * 32768 + n * 32;
        const float* xpw = x_proj_w + (size_t)l * 65536;
        float4 acc[4] = {};
        for (int r = 0; r < 32; r++) {
            const float s = dtw[r];
#pragma unroll
            for (int rep = 0; rep < 4; rep++) {
                const float4 xv = *(const float4*)(xpw + r * 1024 + rep * 256 + lane * 4);
                acc[rep].x = fmaf(s, xv.x, acc[rep].x);
                acc[rep].y = fmaf(s, xv.y, acc[rep].y);
                acc[rep].z = fmaf(s, xv.z, acc[rep].z);
                acc[rep].w = fmaf(s, xv.w, acc[rep].w);
            }
        }
        short* dst = wxpdb + (size_t)l * 1114112 + (size_t)(64 + n) * 1024;
#pragma unroll
        for (int rep = 0; rep < 4; rep++) {
            union { short sh[4]; uint2 u; } pk;
            pk.sh[0] = f2b(acc[rep].x); pk.sh[1] = f2b(acc[rep].y);
            pk.sh[2] = f2b(acc[rep].z); pk.sh[3] = f2b(acc[rep].w);
            *(uint2*)(dst + rep * 256 + lane * 4) = pk.u;
        }
    } else if (blk < 1088) {
#pragma unroll
        for (int rep = 0; rep < 4; rep++) {
            const int e = (blk - 1024) * 4096 + rep * 1024 + tid * 4;  // < 262144
            const int l = e >> 16, rowk = e & 65535;
            const float4 v = *(const float4*)(x_proj_w + (size_t)l * 65536 + rowk);
            union { short sh[4]; uint2 u; } pk;
            pk.sh[0] = f2b(v.x); pk.sh[1] = f2b(v.y); pk.sh[2] = f2b(v.z); pk.sh[3] = f2b(v.w);
            *(uint2*)(wxpdb + (size_t)l * 1114112 + rowk) = pk.u;
        }
    } else if (blk < 2048) {
        constexpr int pre[8] = {0, 128, 256, 512, 4608, 6656, 7680, 7936};
        for (int vb = blk - 1088; vb < 7936; vb += 960) {
            int s = 0;
#pragma unroll
            for (int i = 1; i < 7; i++) s += (vb >= pre[i]);
            const int e = (vb - pre[s]) * 1024 + tid * 4;
            const float* src; short* dst;
            bool hasG = false; const float* gp = nullptr;
            if      (s == 0) { src = lin1_w + e;     dst = wlin1gb + e; }
            else if (s == 1) { src = gate_w + e;     dst = wlin1gb + 131072 + e; }
            else if (s == 2) { src = lin2_w + e;     dst = wlin2b + e; }
            else if (s == 3) { src = in_proj_w + e;  dst = winpb + e;
                               hasG = true; gp = blk_norm_w + (e >> 20) * 512 + (e & 511); }
            else if (s == 4) { src = out_proj_w + e; dst = woutpb + e; }
            else if (s == 5) { src = proj_w + e;     dst = wprojb + e;
                               hasG = true; gp = post_norm_w + (e & 511); }
            else             { src = inputs + e;     dst = inputsb + e; }
            float4 v = *(const float4*)src;
            if (hasG) {
                const float4 gv = *(const float4*)gp;
                v.x *= gv.x; v.y *= gv.y; v.z *= gv.z; v.w *= gv.w;
            }
            union { short sh[4]; uint2 u; } pk;
            pk.sh[0] = f2b(v.x); pk.sh[1] = f2b(v.y); pk.sh[2] = f2b(v.z); pk.sh[3] = f2b(v.w);
            *(uint2*)dst = pk.u;
        }
    } else {
        const int i = (blk - 2048) * 256 + tid;   // < 8192
        if (i < 4096) preds[i] = 0.f;
        else ss[1024 + (i - 4096)] = 0.f;          // zero ss slots 1..4
    }
}

// ================= spatial: lin1|gate merged (N=1024) =================
__global__ __launch_bounds__(256) void lin1gate_k(
    const short* __restrict__ A, const short* __restrict__ W,
    const float* __restrict__ b1, const float* __restrict__ b2,
    short* __restrict__ h1b, float* __restrict__ g)
{
    __shared__ short As[2 * 64 * 32];
    __shared__ short Bs[2 * 64 * 32];
    f32x4 acc[2][2] = {};
    const int m0 = blockIdx.y * 64, n0 = blockIdx.x * 64;
    gemm_core64(acc, A, 256, W, 256, 256, As, Bs, m0, n0);
    const int lane = threadIdx.x & 63, wave = threadIdx.x >> 6;
    const int wm = wave >> 1, wn = wave & 1, l15 = lane & 15, kg = lane >> 4;
#pragma unroll
    for (int ni = 0; ni < 2; ni++) {
        const int col = n0 + wn * 32 + ni * 16 + l15;
        const bool isG = col >= 512;
        const float b = isG ? b2[col - 512] : b1[col];
#pragma unroll
        for (int mi = 0; mi < 2; mi++)
#pragma unroll
            for (int j = 0; j < 4; j++) {
                const int row = m0 + wm * 32 + mi * 16 + kg * 4 + j;
                const float v = acc[mi][ni][j] + b;
                if (isG) g[(size_t)row * 512 + (col - 512)] = sigm(v);
                else     h1b[(size_t)row * 512 + col] = f2b(0.5f * v * (1.f + erff(v * 0.70710678f)));
            }
    }
}

// ================= lin2: x = (h1 @ W^T + b) * g =================
__global__ __launch_bounds__(256) void lin2_k(
    const short* __restrict__ A, const short* __restrict__ W,
    const float* __restrict__ bias, const float* __restrict__ g, float* __restrict__ x)
{
    __shared__ short As[2 * 64 * 32];
    __shared__ short Bs[2 * 64 * 32];
    f32x4 acc[2][2] = {};
    const int m0 = blockIdx.y * 64, n0 = blockIdx.x * 64;
    gemm_core64(acc, A, 512, W, 512, 512, As, Bs, m0, n0);
    const int lane = threadIdx.x & 63, wave = threadIdx.x >> 6;
    const int wm = wave >> 1, wn = wave & 1, l15 = lane & 15, kg = lane >> 4;
#pragma unroll
    for (int ni = 0; ni < 2; ni++) {
        const int col = n0 + wn * 32 + ni * 16 + l15;
        const float b = bias[col];
#pragma unroll
        for (int mi = 0; mi < 2; mi++)
#pragma unroll
            for (int j = 0; j < 4; j++) {
                const int row = m0 + wm * 32 + mi * 16 + kg * 4 + j;
                x[(size_t)row * 512 + col] = (acc[mi][ni][j] + b) * g[(size_t)row * 512 + col];
            }
    }
}

// ================= spatial rmsnorm: h fp32 + hb bf16 + ss[0] =================
__global__ __launch_bounds__(256) void rms_sp_k(
    const float* __restrict__ x, const float* __restrict__ w,
    float* __restrict__ h, short* __restrict__ hb, float* __restrict__ ss0)
{
    const int lane = threadIdx.x & 63;
    const int rowId = blockIdx.x * 4 + (threadIdx.x >> 6);
    const float* ip = x + (size_t)rowId * 512 + lane * 8;
    const float4 v1 = *(const float4*)ip;
    const float4 v2 = *(const float4*)(ip + 4);
    float sq = v1.x * v1.x + v1.y * v1.y + v1.z * v1.z + v1.w * v1.w
             + v2.x * v2.x + v2.y * v2.y + v2.z * v2.z + v2.w * v2.w;
#pragma unroll
    for (int off = 32; off > 0; off >>= 1) sq += __shfl_xor(sq, off, 64);
    const float rs = rsqrtf(sq * (1.f / 512.f) + 1e-5f);
    const float4 w1 = *(const float4*)(w + lane * 8);
    const float4 w2 = *(const float4*)(w + lane * 8 + 4);
    const float o[8] = { v1.x * rs * w1.x, v1.y * rs * w1.y, v1.z * rs * w1.z, v1.w * rs * w1.w,
                         v2.x * rs * w2.x, v2.y * rs * w2.y, v2.z * rs * w2.z, v2.w * rs * w2.w };
    float* op = h + (size_t)rowId * 512 + lane * 8;
    *(float4*)op       = make_float4(o[0], o[1], o[2], o[3]);
    *(float4*)(op + 4) = make_float4(o[4], o[5], o[6], o[7]);
    short8 pk;
#pragma unroll
    for (int i = 0; i < 8; i++) pk[i] = f2b(o[i]);
    *(short8*)(hb + (size_t)rowId * 512 + lane * 8) = pk;
    float s2 = 0.f;
#pragma unroll
    for (int i = 0; i < 8; i++) s2 = fmaf(o[i], o[i], s2);
#pragma unroll
    for (int off = 32; off > 0; off >>= 1) s2 += __shfl_xor(s2, off, 64);
    if (lane == 0) ss0[rowId] = s2;
}

// ================= in_proj + fused depthwise conv + silu (64x64 tile) =================
// Tile = 64 rows (exactly one batch) x 64 cols. n0<1024: conv; n0>=1024: silu(res) bf16.
union ConvU {
    struct { short As[2 * 64 * 32]; short Bs[2 * 64 * 32]; } gm;   // 16 KB (GEMM)
    float cbuf[67][68];                                             // 18.2 KB (conv)
};

__global__ __launch_bounds__(256) void inprojconv_k(
    const short* __restrict__ A, const short* __restrict__ W,
    const float* __restrict__ ss_in, const float* __restrict__ cw,
    const float* __restrict__ cb, short* __restrict__ xcb, short* __restrict__ srb)
{
    __shared__ ConvU u;
    f32x4 acc[2][2] = {};
    const int m0 = blockIdx.y * 64, n0 = blockIdx.x * 64;
    gemm_core64(acc, A, 512, W, 512, 512, u.gm.As, u.gm.Bs, m0, n0);
    const int tid = threadIdx.x;
    const int lane = tid & 63, wave = tid >> 6;
    const int wm = wave >> 1, wn = wave & 1, l15 = lane & 15, kg = lane >> 4;

    // rmsnorm row scale
#pragma unroll
    for (int mi = 0; mi < 2; mi++)
#pragma unroll
        for (int j = 0; j < 4; j++) {
            const int row = m0 + wm * 32 + mi * 16 + kg * 4 + j;
            const float r = rsqrtf(ss_in[row] * (1.f / 512.f) + 1e-5f);
#pragma unroll
            for (int ni = 0; ni < 2; ni++) acc[mi][ni][j] *= r;
        }

    if (n0 < 1024) {
        // single-pass LDS conv: rows 0..63 = one batch; causal zero-pad slots 0..2
        const int ccol = tid & 63;
        const int rg = tid >> 6;           // 0..3
        const int d = n0 + ccol;
        const float4 w4 = *(const float4*)(cw + d * 4);
        const float bia = cb[d];

        __syncthreads();   // gemm LDS reads done
#pragma unroll
        for (int mi = 0; mi < 2; mi++)
#pragma unroll
            for (int ni = 0; ni < 2; ni++)
#pragma unroll
                for (int j = 0; j < 4; j++)
                    u.cbuf[3 + wm * 32 + mi * 16 + kg * 4 + j][wn * 32 + ni * 16 + l15] = acc[mi][ni][j];
        for (int i = tid; i < 3 * 68; i += 256) u.cbuf[i / 68][i % 68] = 0.f;
        __syncthreads();
#pragma unroll 4
        for (int k = 0; k < 16; k++) {
            const int row = rg + 4 * k;    // 0..63
            float v = bia + w4.x * u.cbuf[row][ccol] + w4.y * u.cbuf[row + 1][ccol]
                          + w4.z * u.cbuf[row + 2][ccol] + w4.w * u.cbuf[row + 3][ccol];
            v = v * sigm(v);
            xcb[(size_t)(m0 + row) * 1024 + d] = f2b(v);
        }
    } else {
#pragma unroll
        for (int ni = 0; ni < 2; ni++) {
            const int scol = n0 - 1024 + wn * 32 + ni * 16 + l15;
#pragma unroll
            for (int mi = 0; mi < 2; mi++)
#pragma unroll
                for (int j = 0; j < 4; j++) {
                    const int row = m0 + wm * 32 + mi * 16 + kg * 4 + j;
                    const float v = acc[mi][ni][j];
                    srb[(size_t)row * 1024 + scol] = f2b(v * sigm(v));
                }
        }
    }
}

// ================= xpd: [xdbl | delta] = xcb @ [xpw; W_delta]^T (N=1088) =================
__global__ __launch_bounds__(256) void xpd_k(
    const short* __restrict__ A, const short* __restrict__ W,
    const float* __restrict__ dtb, float* __restrict__ xdbl, float* __restrict__ delta)
{
    __shared__ short As[2 * 64 * 32];
    __shared__ short Bs[2 * 64 * 32];
    f32x4 acc[2][2] = {};
    const int m0 = blockIdx.y * 64, n0 = blockIdx.x * 64;
    gemm_core64(acc, A, 1024, W, 1024, 1024, As, Bs, m0, n0);
    const int lane = threadIdx.x & 63, wave = threadIdx.x >> 6;
    const int wm = wave >> 1, wn = wave & 1, l15 = lane & 15, kg = lane >> 4;
#pragma unroll
    for (int ni = 0; ni < 2; ni++) {
        const int col = n0 + wn * 32 + ni * 16 + l15;
#pragma unroll
        for (int mi = 0; mi < 2; mi++)
#pragma unroll
            for (int j = 0; j < 4; j++) {
                const int row = m0 + wm * 32 + mi * 16 + kg * 4 + j;
                const float v = acc[mi][ni][j];
                if (col < 64) xdbl[(size_t)row * 64 + col] = v;
                else          delta[(size_t)row * 1024 + (col - 64)] = softp(v + dtb[col - 64]);
            }
    }
}

// ================= scan: 256 blocks x 64 thr, load-pipelined =================
__global__ __launch_bounds__(64) void scan_k(
    const short* __restrict__ xcb, const float* __restrict__ delta,
    const float* __restrict__ xdbl, const float* __restrict__ Alog,
    const float* __restrict__ Dp, const short* __restrict__ srb, short* __restrict__ yb)
{
    const int b = blockIdx.x >> 4;
    const int d = ((blockIdx.x & 15) << 6) + threadIdx.x;
    __shared__ float Bsh[SEQ][DFF];
    __shared__ float Csh[SEQ][DFF];
    for (int i = threadIdx.x; i < SEQ * DFF; i += 64) {
        const int l = i >> 4, n = i & 15;
        Bsh[l][n] = xdbl[(size_t)(b * SEQ + l) * 64 + DTRANK + n];
        Csh[l][n] = xdbl[(size_t)(b * SEQ + l) * 64 + DTRANK + DFF + n];
    }
    __syncthreads();
    float a[16], s[16];
#pragma unroll
    for (int n = 0; n < 16; n++) { a[n] = -__expf(Alog[(size_t)d * 16 + n]); s[n] = 0.f; }
    const float dv = Dp[d];
    const size_t base = (size_t)b * SEQ;
    float dlt = delta[base * DINNER + d];
    float uu  = b2f(xcb[base * DINNER + d]);
    float rr  = b2f(srb[base * 1024 + d]);
    for (int l = 0; l < SEQ; l++) {
        float dlt_n = 0.f, uu_n = 0.f, rr_n = 0.f;
        if (l + 1 < SEQ) {       // prefetch next step's operands (hides load latency)
            const size_t mn = base + l + 1;
            dlt_n = delta[mn * DINNER + d];
            uu_n  = b2f(xcb[mn * DINNER + d]);
            rr_n  = b2f(srb[mn * 1024 + d]);
        }
        const float dbu = dlt * uu;
        float acc = 0.f;
#pragma unroll
        for (int n = 0; n < 16; n++) {
            s[n] = __expf(dlt * a[n]) * s[n] + dbu * Bsh[l][n];
            acc = fmaf(s[n], Csh[l][n], acc);
        }
        acc = fmaf(uu, dv, acc);
        yb[(base + l) * DINNER + d] = f2b(acc * rr);
        dlt = dlt_n; uu = uu_n; rr = rr_n;
    }
}

// ================= out_proj: h += yb @ W^T; writes h fp32 + hb bf16 + ss_out =========
__global__ __launch_bounds__(256) void outproj_k(
    const short* __restrict__ A, const short* __restrict__ W,
    float* __restrict__ h, short* __restrict__ hb, float* __restrict__ ss_out)
{
    __shared__ short As[2 * 64 * 32];
    __shared__ short Bs[2 * 64 * 32];
    f32x4 acc[2][2] = {};
    const int m0 = blockIdx.y * 64, n0 = blockIdx.x * 64;
    gemm_core64(acc, A, 1024, W, 1024, 1024, As, Bs, m0, n0);
    const int lane = threadIdx.x & 63, wave = threadIdx.x >> 6;
    const int wm = wave >> 1, wn = wave & 1, l15 = lane & 15, kg = lane >> 4;
    float vsq[2][4] = {};
#pragma unroll
    for (int ni = 0; ni < 2; ni++) {
        const int col = n0 + wn * 32 + ni * 16 + l15;
#pragma unroll
        for (int mi = 0; mi < 2; mi++)
#pragma unroll
            for (int j = 0; j < 4; j++) {
                const int row = m0 + wm * 32 + mi * 16 + kg * 4 + j;
                const float v = acc[mi][ni][j] + h[(size_t)row * 512 + col];
                h[(size_t)row * 512 + col] = v;
                hb[(size_t)row * 512 + col] = f2b(v);
                vsq[mi][j] = fmaf(v, v, vsq[mi][j]);
            }
    }
#pragma unroll
    for (int mi = 0; mi < 2; mi++)
#pragma unroll
        for (int j = 0; j < 4; j++) {
            float t = vsq[mi][j];
            t += __shfl_xor(t, 1, 64);
            t += __shfl_xor(t, 2, 64);
            t += __shfl_xor(t, 4, 64);
            t += __shfl_xor(t, 8, 64);
            if (l15 == 0) {
                const int row = m0 + wm * 32 + mi * 16 + kg * 4 + j;
                atomicAdd(ss_out + row, t);
            }
        }
}

// ================= final proj: xr = r[row] * (hb @ (W.gamma)^T) =================
__global__ __launch_bounds__(256) void projf_k(
    const short* __restrict__ A, const short* __restrict__ W,
    const float* __restrict__ ss_in, float* __restrict__ xr)
{
    __shared__ short As[2 * 64 * 32];
    __shared__ short Bs[2 * 64 * 32];
    f32x4 acc[2][2] = {};
    const int m0 = blockIdx.y * 64, n0 = blockIdx.x * 64;
    gemm_core64(acc, A, 512, W, 512, 512, As, Bs, m0, n0);
    const int lane = threadIdx.x & 63, wave = threadIdx.x >> 6;
    const int wm = wave >> 1, wn = wave & 1, l15 = lane & 15, kg = lane >> 4;
#pragma unroll
    for (int mi = 0; mi < 2; mi++)
#pragma unroll
        for (int j = 0; j < 4; j++) {
            const int row = m0 + wm * 32 + mi * 16 + kg * 4 + j;
            const float r = rsqrtf(ss_in[row] * (1.f / 512.f) + 1e-5f);
#pragma unroll
            for (int ni = 0; ni < 2; ni++) {
                const int col = n0 + wn * 32 + ni * 16 + l15;
                xr[(size_t)row * 2048 + col] = acc[mi][ni][j] * r;
            }
        }
}

// ================= coeffs + preds =================
__global__ __launch_bounds__(256) void coeffs_k(
    const float* __restrict__ outp, const float* __restrict__ inp,
    float* __restrict__ coeffs, float* __restrict__ preds)
{
    const int m = blockIdx.x;
    const int b = m >> 6;
    const int tid = threadIdx.x, wave = tid >> 6, lane = tid & 63;
    __shared__ float4 Us[256], Vs[256];
    __shared__ float ins[256];
    __shared__ float4 tpart[4];
    Us[tid] = *(const float4*)(outp + (size_t)m * 2048 + tid * 4);
    Vs[tid] = *(const float4*)(outp + (size_t)m * 2048 + 1024 + tid * 4);
    ins[tid] = inp[(size_t)m * 256 + tid];
    __syncthreads();
    const float4 vq0 = Vs[lane * 4 + 0], vq1 = Vs[lane * 4 + 1];
    const float4 vq2 = Vs[lane * 4 + 2], vq3 = Vs[lane * 4 + 3];
    float* cbase = coeffs + (size_t)m * 65536 + lane * 4;
#pragma unroll 4
    for (int i = 0; i < 64; i++) {
        const int pp = (wave << 6) + i;
        const float4 up = Us[pp];
        float4 c;
        c.x = up.x * vq0.x + up.y * vq0.y + up.z * vq0.z + up.w * vq0.w;
        c.y = up.x * vq1.x + up.y * vq1.y + up.z * vq1.z + up.w * vq1.w;
        c.z = up.x * vq2.x + up.y * vq2.y + up.z * vq2.z + up.w * vq2.w;
        c.w = up.x * vq3.x + up.y * vq3.y + up.z * vq3.z + up.w * vq3.w;
        *(float4*)(cbase + (size_t)pp * 256) = c;
    }
    const float iv = ins[tid];
    const float4 vm = Vs[tid];
    float4 t = make_float4(vm.x * iv, vm.y * iv, vm.z * iv, vm.w * iv);
#pragma unroll
    for (int off = 32; off > 0; off >>= 1) {
        t.x += __shfl_xor(t.x, off, 64);
        t.y += __shfl_xor(t.y, off, 64);
        t.z += __shfl_xor(t.z, off, 64);
        t.w += __shfl_xor(t.w, off, 64);
    }
    if (lane == 0) tpart[wave] = t;
    __syncthreads();
    const float4 t0 = tpart[0], t1 = tpart[1], t2 = tpart[2], t3 = tpart[3];
    const float4 tt = make_float4(t0.x + t1.x + t2.x + t3.x, t0.y + t1.y + t2.y + t3.y,
                                  t0.z + t1.z + t2.z + t3.z, t0.w + t1.w + t2.w + t3.w);
    const float4 up = Us[tid];
    const float pv = up.x * tt.x + up.y * tt.y + up.z * tt.z + up.w * tt.w;
    atomicAdd(preds + (size_t)b * 256 + tid, pv);
}

} // namespace

extern "C" void kernel_launch(void* const* d_in, const int* in_sizes, int n_in,
                              void* d_out, int out_size, void* d_ws, size_t ws_size,
                              hipStream_t stream)
{
    const float* inputs     = (const float*)d_in[0];
    const float* lin1_w     = (const float*)d_in[1];
    const float* lin1_b     = (const float*)d_in[2];
    const float* lin2_w     = (const float*)d_in[3];
    const float* lin2_b     = (const float*)d_in[4];
    const float* gate_w     = (const float*)d_in[5];
    const float* gate_b     = (const float*)d_in[6];
    const float* sp_norm_w  = (const float*)d_in[7];
    const float* in_proj_w  = (const float*)d_in[8];
    const float* conv_w     = (const float*)d_in[9];
    const float* conv_b     = (const float*)d_in[10];
    const float* x_proj_w   = (const float*)d_in[11];
    const float* dt_proj_w  = (const float*)d_in[12];
    const float* dt_proj_b  = (const float*)d_in[13];
    const float* A_log      = (const float*)d_in[14];
    const float* Dvec       = (const float*)d_in[15];
    const float* out_proj_w = (const float*)d_in[16];
    const float* blk_norm_w = (const float*)d_in[17];
    const float* post_norm_w= (const float*)d_in[18];
    const float* proj_w     = (const float*)d_in[19];

    float* ws = (float*)d_ws;
    // fp32 region
    float* h     = ws;                 // 1024 x 512
    float* xr    = ws + 524288;        // 1024 x 2048 (final proj out)
    float* x     = ws + 2621440;       // 1024 x 512 (lin2 out)
    float* g     = ws + 3145728;       // 1024 x 512
    float* delta = ws + 3670016;       // 1024 x 1024
    float* xdbl  = ws + 4718592;       // 1024 x 64
    float* ss    = ws + 4784128;       // 5 x 1024 sumsq slots
    // bf16 region
    short* bfb     = (short*)(ws + 4790272);
    short* inputsb = bfb;               // 1024 x 256
    short* h1b     = bfb + 262144;      // 1024 x 512
    short* hb      = bfb + 786432;      // 1024 x 512
    short* xcb     = bfb + 1310720;     // 1024 x 1024
    short* yb      = bfb + 2359296;     // 1024 x 1024
    short* srb     = bfb + 3407872;     // 1024 x 1024 silu(res)
    short* wlin1gb = bfb + 4456448;     // 1024 x 256
    short* wlin2b  = bfb + 4718592;     // 512 x 512
    short* winpb   = bfb + 4980736;     // 4 x 2048 x 512 (gamma-folded)
    short* woutpb  = bfb + 9175040;     // 4 x 512 x 1024
    short* wprojb  = bfb + 11272192;    // 2048 x 512 (gamma-folded)
    short* wxpdb   = bfb + 12320768;    // 4 x 1088 x 1024 ([xpw; W_delta])
    float* preds  = (float*)d_out;
    float* coeffs = (float*)d_out + 4096;

    const dim3 blk(256);

    prep_k<<<dim3(2080), blk, 0, stream>>>(
        lin1_w, gate_w, lin2_w, in_proj_w, out_proj_w, proj_w, x_proj_w, dt_proj_w,
        inputs, blk_norm_w, post_norm_w,
        wlin1gb, wlin2b, winpb, woutpb, wprojb, wxpdb, inputsb, preds, ss);

    lin1gate_k<<<dim3(16, 16), blk, 0, stream>>>(inputsb, wlin1gb, lin1_b, gate_b, h1b, g);
    lin2_k<<<dim3(8, 16), blk, 0, stream>>>(h1b, wlin2b, lin2_b, g, x);
    rms_sp_k<<<dim3(256), blk, 0, stream>>>(x, sp_norm_w, h, hb, ss);

    for (int l = 0; l < 4; l++) {
        inprojconv_k<<<dim3(32, 16), blk, 0, stream>>>(
            hb, winpb + (size_t)l * 1048576, ss + l * 1024,
            conv_w + (size_t)l * 4096, conv_b + l * 1024, xcb, srb);
        xpd_k<<<dim3(17, 16), blk, 0, stream>>>(xcb, wxpdb + (size_t)l * 1114112,
                                                dt_proj_b + l * 1024, xdbl, delta);
        scan_k<<<dim3(256), dim3(64), 0, stream>>>(xcb, delta, xdbl, A_log + (size_t)l * 16384,
                                                   Dvec + l * 1024, srb, yb);
        outproj_k<<<dim3(8, 16), blk, 0, stream>>>(yb, woutpb + (size_t)l * 524288,
                                                   h, hb, ss + (l + 1) * 1024);
    }

    projf_k<<<dim3(32, 16), blk, 0, stream>>>(hb, wprojb, ss + 4096, xr);
    coeffs_k<<<dim3(1024), blk, 0, stream>>>(xr, inputs, coeffs, preds);
}

// Round 9
// 422.953 us; speedup vs baseline: 1.8820x; 1.1349x over previous
//
#include <hip/hip_runtime.h>
#include <hip/hip_bf16.h>
#include <math.h>

namespace {

constexpr int SEQ    = 64;
constexpr int DINNER = 1024;
constexpr int DFF    = 16;
constexpr int DTRANK = 32;

typedef __attribute__((ext_vector_type(8))) short short8;
typedef __attribute__((ext_vector_type(4))) float f32x4;
typedef __attribute__((address_space(3))) unsigned int lds_u32_t;
typedef __attribute__((address_space(1))) unsigned int glb_u32_t;

__device__ __forceinline__ float sigm(float x) { return 1.f / (1.f + __expf(-x)); }
__device__ __forceinline__ short f2b(float v) {
    __hip_bfloat16 h = __float2bfloat16(v);
    return *(short*)&h;
}
__device__ __forceinline__ float b2f(short s) {
    union { unsigned u; float f; } c; c.u = ((unsigned)(unsigned short)s) << 16; return c.f;
}
__device__ __forceinline__ float softp(float v) {
    return fmaxf(v, 0.f) + log1pf(__expf(-fabsf(v)));
}

// ====== bf16 MFMA GEMM core, 64x64 tile, 2-phase pipelined (R8, verified) ======
__device__ __forceinline__ void gemm_core64(
    f32x4 (&acc)[2][2],
    const short* __restrict__ A, int lda,
    const short* __restrict__ W, int ldw,
    int Kd, short* As, short* Bs, int m0, int n0)
{
    constexpr int SZ = 64 * 32;
    const int tid = threadIdx.x, wave = tid >> 6, lane = tid & 63;
    const int wm = wave >> 1, wn = wave & 1;
    const int l15 = lane & 15, kg = lane >> 4;

    const int p = wave * 64 + lane;   // 16B chunk: row p>>2, slot p&3
    const short* srcA = A + (size_t)(m0 + (p >> 2)) * lda + (p & 3) * 8;
    const short* srcB = W + (size_t)(n0 + (p >> 2)) * ldw + (p & 3) * 8;
    const int ob = (wave * 64) * 8;   // wave-uniform LDS base (shorts)

    const int nt = Kd >> 5;
    __builtin_amdgcn_global_load_lds((const glb_u32_t*)srcA, (lds_u32_t*)(As + ob), 16, 0, 0);
    __builtin_amdgcn_global_load_lds((const glb_u32_t*)srcB, (lds_u32_t*)(Bs + ob), 16, 0, 0);

    for (int t = 0; t < nt; t++) {
        __syncthreads();   // drains stage for buf[t&1] + prior ds_reads
        if (t + 1 < nt) {
            const int k0 = (t + 1) * 32;
            const int s = ((t + 1) & 1) * SZ;
            __builtin_amdgcn_global_load_lds((const glb_u32_t*)(srcA + k0), (lds_u32_t*)(As + s + ob), 16, 0, 0);
            __builtin_amdgcn_global_load_lds((const glb_u32_t*)(srcB + k0), (lds_u32_t*)(Bs + s + ob), 16, 0, 0);
        }
        const short* Ab = As + (t & 1) * SZ;
        const short* Bb = Bs + (t & 1) * SZ;
        short8 af[2], bfr[2];
#pragma unroll
        for (int mi = 0; mi < 2; mi++)
            af[mi] = *(const short8*)(Ab + (wm * 32 + mi * 16 + l15) * 32 + kg * 8);
#pragma unroll
        for (int ni = 0; ni < 2; ni++)
            bfr[ni] = *(const short8*)(Bb + (wn * 32 + ni * 16 + l15) * 32 + kg * 8);
#pragma unroll
        for (int mi = 0; mi < 2; mi++)
#pragma unroll
            for (int ni = 0; ni < 2; ni++)
                acc[mi][ni] = __builtin_amdgcn_mfma_f32_16x16x32_bf16(af[mi], bfr[ni], acc[mi][ni], 0, 0, 0);
    }
}
// C/D frag [m89]: col = n0 + wn*32 + ni*16 + (lane&15);
//                 row = m0 + wm*32 + mi*16 + (lane>>4)*4 + j

// ================= prep: conversions (+gamma fold), W_delta, zeroing =================
__global__ __launch_bounds__(256) void prep_k(
    const float* __restrict__ lin1_w, const float* __restrict__ gate_w,
    const float* __restrict__ lin2_w, const float* __restrict__ in_proj_w,
    const float* __restrict__ out_proj_w, const float* __restrict__ proj_w,
    const float* __restrict__ x_proj_w, const float* __restrict__ dt_proj_w,
    const float* __restrict__ inputs, const float* __restrict__ blk_norm_w,
    const float* __restrict__ post_norm_w,
    short* __restrict__ wlin1gb, short* __restrict__ wlin2b, short* __restrict__ winpb,
    short* __restrict__ woutpb, short* __restrict__ wprojb, short* __restrict__ wxpdb,
    short* __restrict__ inputsb, float* __restrict__ preds, float* __restrict__ ss)
{
    const int blk = blockIdx.x, tid = threadIdx.x;
    if (blk < 1024) {
        // W_delta = dt_w(1024x32) @ xp_w[:32](32x1024), per layer; wave per n-row
        const int wave = tid >> 6, lane = tid & 63;
        const int nrow = blk * 4 + wave;          // 0..4095
        const int l = nrow >> 10, n = nrow & 1023;
        const float* dtw = dt_proj_w + (size_t)l * 32768 + n * 32;
        const float* xpw = x_proj_w + (size_t)l * 65536;
        float4 acc[4] = {};
        for (int r = 0; r < 32; r++) {
            const float s = dtw[r];
#pragma unroll
            for (int rep = 0; rep < 4; rep++) {
                const float4 xv = *(const float4*)(xpw + r * 1024 + rep * 256 + lane * 4);
                acc[rep].x = fmaf(s, xv.x, acc[rep].x);
                acc[rep].y = fmaf(s, xv.y, acc[rep].y);
                acc[rep].z = fmaf(s, xv.z, acc[rep].z);
                acc[rep].w = fmaf(s, xv.w, acc[rep].w);
            }
        }
        short* dst = wxpdb + (size_t)l * 1114112 + (size_t)(64 + n) * 1024;
#pragma unroll
        for (int rep = 0; rep < 4; rep++) {
            union { short sh[4]; uint2 u; } pk;
            pk.sh[0] = f2b(acc[rep].x); pk.sh[1] = f2b(acc[rep].y);
            pk.sh[2] = f2b(acc[rep].z); pk.sh[3] = f2b(acc[rep].w);
            *(uint2*)(dst + rep * 256 + lane * 4) = pk.u;
        }
    } else if (blk < 1088) {
#pragma unroll
        for (int rep = 0; rep < 4; rep++) {
            const int e = (blk - 1024) * 4096 + rep * 1024 + tid * 4;  // < 262144
            const int l = e >> 16, rowk = e & 65535;
            const float4 v = *(const float4*)(x_proj_w + (size_t)l * 65536 + rowk);
            union { short sh[4]; uint2 u; } pk;
            pk.sh[0] = f2b(v.x); pk.sh[1] = f2b(v.y); pk.sh[2] = f2b(v.z); pk.sh[3] = f2b(v.w);
            *(uint2*)(wxpdb + (size_t)l * 1114112 + rowk) = pk.u;
        }
    } else if (blk < 2048) {
        constexpr int pre[8] = {0, 128, 256, 512, 4608, 6656, 7680, 7936};
        for (int vb = blk - 1088; vb < 7936; vb += 960) {
            int s = 0;
#pragma unroll
            for (int i = 1; i < 7; i++) s += (vb >= pre[i]);
            const int e = (vb - pre[s]) * 1024 + tid * 4;
            const float* src; short* dst;
            bool hasG = false; const float* gp = nullptr;
            if      (s == 0) { src = lin1_w + e;     dst = wlin1gb + e; }
            else if (s == 1) { src = gate_w + e;     dst = wlin1gb + 131072 + e; }
            else if (s == 2) { src = lin2_w + e;     dst = wlin2b + e; }
            else if (s == 3) { src = in_proj_w + e;  dst = winpb + e;
                               hasG = true; gp = blk_norm_w + (e >> 20) * 512 + (e & 511); }
            else if (s == 4) { src = out_proj_w + e; dst = woutpb + e; }
            else if (s == 5) { src = proj_w + e;     dst = wprojb + e;
                               hasG = true; gp = post_norm_w + (e & 511); }
            else             { src = inputs + e;     dst = inputsb + e; }
            float4 v = *(const float4*)src;
            if (hasG) {
                const float4 gv = *(const float4*)gp;
                v.x *= gv.x; v.y *= gv.y; v.z *= gv.z; v.w *= gv.w;
            }
            union { short sh[4]; uint2 u; } pk;
            pk.sh[0] = f2b(v.x); pk.sh[1] = f2b(v.y); pk.sh[2] = f2b(v.z); pk.sh[3] = f2b(v.w);
            *(uint2*)dst = pk.u;
        }
    } else {
        const int i = (blk - 2048) * 256 + tid;   // < 8192
        if (i < 4096) preds[i] = 0.f;
        else ss[1024 + (i - 4096)] = 0.f;          // zero ss slots 1..4
    }
}

// ================= spatial: lin1|gate merged (N=1024) =================
__global__ __launch_bounds__(256) void lin1gate_k(
    const short* __restrict__ A, const short* __restrict__ W,
    const float* __restrict__ b1, const float* __restrict__ b2,
    short* __restrict__ h1b, float* __restrict__ g)
{
    __shared__ short As[2 * 64 * 32];
    __shared__ short Bs[2 * 64 * 32];
    f32x4 acc[2][2] = {};
    const int m0 = blockIdx.y * 64, n0 = blockIdx.x * 64;
    gemm_core64(acc, A, 256, W, 256, 256, As, Bs, m0, n0);
    const int lane = threadIdx.x & 63, wave = threadIdx.x >> 6;
    const int wm = wave >> 1, wn = wave & 1, l15 = lane & 15, kg = lane >> 4;
#pragma unroll
    for (int ni = 0; ni < 2; ni++) {
        const int col = n0 + wn * 32 + ni * 16 + l15;
        const bool isG = col >= 512;
        const float b = isG ? b2[col - 512] : b1[col];
#pragma unroll
        for (int mi = 0; mi < 2; mi++)
#pragma unroll
            for (int j = 0; j < 4; j++) {
                const int row = m0 + wm * 32 + mi * 16 + kg * 4 + j;
                const float v = acc[mi][ni][j] + b;
                if (isG) g[(size_t)row * 512 + (col - 512)] = sigm(v);
                else     h1b[(size_t)row * 512 + col] = f2b(0.5f * v * (1.f + erff(v * 0.70710678f)));
            }
    }
}

// ================= lin2: x = (h1 @ W^T + b) * g =================
__global__ __launch_bounds__(256) void lin2_k(
    const short* __restrict__ A, const short* __restrict__ W,
    const float* __restrict__ bias, const float* __restrict__ g, float* __restrict__ x)
{
    __shared__ short As[2 * 64 * 32];
    __shared__ short Bs[2 * 64 * 32];
    f32x4 acc[2][2] = {};
    const int m0 = blockIdx.y * 64, n0 = blockIdx.x * 64;
    gemm_core64(acc, A, 512, W, 512, 512, As, Bs, m0, n0);
    const int lane = threadIdx.x & 63, wave = threadIdx.x >> 6;
    const int wm = wave >> 1, wn = wave & 1, l15 = lane & 15, kg = lane >> 4;
#pragma unroll
    for (int ni = 0; ni < 2; ni++) {
        const int col = n0 + wn * 32 + ni * 16 + l15;
        const float b = bias[col];
#pragma unroll
        for (int mi = 0; mi < 2; mi++)
#pragma unroll
            for (int j = 0; j < 4; j++) {
                const int row = m0 + wm * 32 + mi * 16 + kg * 4 + j;
                x[(size_t)row * 512 + col] = (acc[mi][ni][j] + b) * g[(size_t)row * 512 + col];
            }
    }
}

// ================= spatial rmsnorm: h fp32 + hb bf16 + ss[0] =================
__global__ __launch_bounds__(256) void rms_sp_k(
    const float* __restrict__ x, const float* __restrict__ w,
    float* __restrict__ h, short* __restrict__ hb, float* __restrict__ ss0)
{
    const int lane = threadIdx.x & 63;
    const int rowId = blockIdx.x * 4 + (threadIdx.x >> 6);
    const float* ip = x + (size_t)rowId * 512 + lane * 8;
    const float4 v1 = *(const float4*)ip;
    const float4 v2 = *(const float4*)(ip + 4);
    float sq = v1.x * v1.x + v1.y * v1.y + v1.z * v1.z + v1.w * v1.w
             + v2.x * v2.x + v2.y * v2.y + v2.z * v2.z + v2.w * v2.w;
#pragma unroll
    for (int off = 32; off > 0; off >>= 1) sq += __shfl_xor(sq, off, 64);
    const float rs = rsqrtf(sq * (1.f / 512.f) + 1e-5f);
    const float4 w1 = *(const float4*)(w + lane * 8);
    const float4 w2 = *(const float4*)(w + lane * 8 + 4);
    const float o[8] = { v1.x * rs * w1.x, v1.y * rs * w1.y, v1.z * rs * w1.z, v1.w * rs * w1.w,
                         v2.x * rs * w2.x, v2.y * rs * w2.y, v2.z * rs * w2.z, v2.w * rs * w2.w };
    float* op = h + (size_t)rowId * 512 + lane * 8;
    *(float4*)op       = make_float4(o[0], o[1], o[2], o[3]);
    *(float4*)(op + 4) = make_float4(o[4], o[5], o[6], o[7]);
    short8 pk;
#pragma unroll
    for (int i = 0; i < 8; i++) pk[i] = f2b(o[i]);
    *(short8*)(hb + (size_t)rowId * 512 + lane * 8) = pk;
    float s2 = 0.f;
#pragma unroll
    for (int i = 0; i < 8; i++) s2 = fmaf(o[i], o[i], s2);
#pragma unroll
    for (int off = 32; off > 0; off >>= 1) s2 += __shfl_xor(s2, off, 64);
    if (lane == 0) ss0[rowId] = s2;
}

// ================= in_proj + fused depthwise conv + silu (64x64 tile) =================
union ConvU {
    struct { short As[2 * 64 * 32]; short Bs[2 * 64 * 32]; } gm;   // 16 KB (GEMM)
    float cbuf[67][68];                                             // 18.2 KB (conv)
};

__global__ __launch_bounds__(256) void inprojconv_k(
    const short* __restrict__ A, const short* __restrict__ W,
    const float* __restrict__ ss_in, const float* __restrict__ cw,
    const float* __restrict__ cb, short* __restrict__ xcb, short* __restrict__ srb)
{
    __shared__ ConvU u;
    f32x4 acc[2][2] = {};
    const int m0 = blockIdx.y * 64, n0 = blockIdx.x * 64;
    gemm_core64(acc, A, 512, W, 512, 512, u.gm.As, u.gm.Bs, m0, n0);
    const int tid = threadIdx.x;
    const int lane = tid & 63, wave = tid >> 6;
    const int wm = wave >> 1, wn = wave & 1, l15 = lane & 15, kg = lane >> 4;

#pragma unroll
    for (int mi = 0; mi < 2; mi++)
#pragma unroll
        for (int j = 0; j < 4; j++) {
            const int row = m0 + wm * 32 + mi * 16 + kg * 4 + j;
            const float r = rsqrtf(ss_in[row] * (1.f / 512.f) + 1e-5f);
#pragma unroll
            for (int ni = 0; ni < 2; ni++) acc[mi][ni][j] *= r;
        }

    if (n0 < 1024) {
        const int ccol = tid & 63;
        const int rg = tid >> 6;           // 0..3
        const int d = n0 + ccol;
        const float4 w4 = *(const float4*)(cw + d * 4);
        const float bia = cb[d];

        __syncthreads();   // gemm LDS reads done
#pragma unroll
        for (int mi = 0; mi < 2; mi++)
#pragma unroll
            for (int ni = 0; ni < 2; ni++)
#pragma unroll
                for (int j = 0; j < 4; j++)
                    u.cbuf[3 + wm * 32 + mi * 16 + kg * 4 + j][wn * 32 + ni * 16 + l15] = acc[mi][ni][j];
        for (int i = tid; i < 3 * 68; i += 256) u.cbuf[i / 68][i % 68] = 0.f;
        __syncthreads();
#pragma unroll 4
        for (int k = 0; k < 16; k++) {
            const int row = rg + 4 * k;    // 0..63
            float v = bia + w4.x * u.cbuf[row][ccol] + w4.y * u.cbuf[row + 1][ccol]
                          + w4.z * u.cbuf[row + 2][ccol] + w4.w * u.cbuf[row + 3][ccol];
            v = v * sigm(v);
            xcb[(size_t)(m0 + row) * 1024 + d] = f2b(v);
        }
    } else {
#pragma unroll
        for (int ni = 0; ni < 2; ni++) {
            const int scol = n0 - 1024 + wn * 32 + ni * 16 + l15;
#pragma unroll
            for (int mi = 0; mi < 2; mi++)
#pragma unroll
                for (int j = 0; j < 4; j++) {
                    const int row = m0 + wm * 32 + mi * 16 + kg * 4 + j;
                    const float v = acc[mi][ni][j];
                    srb[(size_t)row * 1024 + scol] = f2b(v * sigm(v));
                }
        }
    }
}

// ================= fused x_proj/dt + selective scan =================
// grid (16 dgroups, 16 batches). Per block: GEMM delta tile (K=1024, W_delta rows)
// + GEMM xdbl tile (n0=0; B/C in cols 32..63) -> LDS -> scan 64 d's.
// K=1024 -> nt=32 even: 2nd gemm's buf0 prologue can't collide with 1st's buf1 tail.
union XsU {
    struct { short As[2 * 64 * 32]; short Bs[2 * 64 * 32]; } gm;   // 16 KB
    struct { float dlt[64][68]; float BC[64][32]; } sc;             // 25.6 KB
};

__global__ __launch_bounds__(256) void xpdscan_k(
    const short* __restrict__ A /*xcb*/, const short* __restrict__ W /*wxpdb layer*/,
    const float* __restrict__ dtb, const float* __restrict__ Alog,
    const float* __restrict__ Dp, const short* __restrict__ srb, short* __restrict__ yb)
{
    __shared__ XsU u;
    const int dg = blockIdx.x, b = blockIdx.y;
    const int m0 = b * 64;
    const int tid = threadIdx.x;
    const int lane = tid & 63, wave = tid >> 6;
    const int wm = wave >> 1, wn = wave & 1, l15 = lane & 15, kg = lane >> 4;

    f32x4 accd[2][2] = {};
    gemm_core64(accd, A, 1024, W, 1024, 1024, u.gm.As, u.gm.Bs, m0, 64 + dg * 64);
    f32x4 accx[2][2] = {};
    gemm_core64(accx, A, 1024, W, 1024, 1024, u.gm.As, u.gm.Bs, m0, 0);

    __syncthreads();   // all gemm LDS reads done before repurposing LDS
    // delta -> LDS (softplus applied); cols of tile = d_local 0..63
#pragma unroll
    for (int ni = 0; ni < 2; ni++) {
        const int dl = wn * 32 + ni * 16 + l15;
        const float bb = dtb[dg * 64 + dl];
#pragma unroll
        for (int mi = 0; mi < 2; mi++)
#pragma unroll
            for (int j = 0; j < 4; j++)
                u.sc.dlt[wm * 32 + mi * 16 + kg * 4 + j][dl] = softp(accd[mi][ni][j] + bb);
    }
    // B/C (xdbl cols 32..63) -> LDS; only wn==1 waves hold those cols
    if (wn == 1) {
#pragma unroll
        for (int ni = 0; ni < 2; ni++) {
            const int c = ni * 16 + l15;   // 0..31 -> BC col
#pragma unroll
            for (int mi = 0; mi < 2; mi++)
#pragma unroll
                for (int j = 0; j < 4; j++)
                    u.sc.BC[wm * 32 + mi * 16 + kg * 4 + j][c] = accx[mi][ni][j];
        }
    }
    __syncthreads();

    if (tid < 64) {
        const int d = dg * 64 + tid;
        float a[16], s[16];
#pragma unroll
        for (int n = 0; n < 16; n++) { a[n] = -__expf(Alog[(size_t)d * 16 + n]); s[n] = 0.f; }
        const float dv = Dp[d];
        const size_t base = (size_t)b * SEQ;
        float uu = b2f(A[base * DINNER + d]);        // A==xcb
        float rr = b2f(srb[base * 1024 + d]);
        for (int l = 0; l < SEQ; l++) {
            float uu_n = 0.f, rr_n = 0.f;
            if (l + 1 < SEQ) {
                uu_n = b2f(A[(base + l + 1) * DINNER + d]);
                rr_n = b2f(srb[(base + l + 1) * 1024 + d]);
            }
            const float dlt = u.sc.dlt[l][tid];
            const float dbu = dlt * uu;
            float acc = 0.f;
#pragma unroll
            for (int n = 0; n < 16; n++) {
                s[n] = __expf(dlt * a[n]) * s[n] + dbu * u.sc.BC[l][n];
                acc = fmaf(s[n], u.sc.BC[l][16 + n], acc);
            }
            acc = fmaf(uu, dv, acc);
            yb[(base + l) * DINNER + d] = f2b(acc * rr);
            uu = uu_n; rr = rr_n;
        }
    }
}

// ================= out_proj: h += yb @ W^T; writes h fp32 + hb bf16 + ss_out =========
__global__ __launch_bounds__(256) void outproj_k(
    const short* __restrict__ A, const short* __restrict__ W,
    float* __restrict__ h, short* __restrict__ hb, float* __restrict__ ss_out)
{
    __shared__ short As[2 * 64 * 32];
    __shared__ short Bs[2 * 64 * 32];
    f32x4 acc[2][2] = {};
    const int m0 = blockIdx.y * 64, n0 = blockIdx.x * 64;
    gemm_core64(acc, A, 1024, W, 1024, 1024, As, Bs, m0, n0);
    const int lane = threadIdx.x & 63, wave = threadIdx.x >> 6;
    const int wm = wave >> 1, wn = wave & 1, l15 = lane & 15, kg = lane >> 4;
    float vsq[2][4] = {};
#pragma unroll
    for (int ni = 0; ni < 2; ni++) {
        const int col = n0 + wn * 32 + ni * 16 + l15;
#pragma unroll
        for (int mi = 0; mi < 2; mi++)
#pragma unroll
            for (int j = 0; j < 4; j++) {
                const int row = m0 + wm * 32 + mi * 16 + kg * 4 + j;
                const float v = acc[mi][ni][j] + h[(size_t)row * 512 + col];
                h[(size_t)row * 512 + col] = v;
                hb[(size_t)row * 512 + col] = f2b(v);
                vsq[mi][j] = fmaf(v, v, vsq[mi][j]);
            }
    }
#pragma unroll
    for (int mi = 0; mi < 2; mi++)
#pragma unroll
        for (int j = 0; j < 4; j++) {
            float t = vsq[mi][j];
            t += __shfl_xor(t, 1, 64);
            t += __shfl_xor(t, 2, 64);
            t += __shfl_xor(t, 4, 64);
            t += __shfl_xor(t, 8, 64);
            if (l15 == 0) {
                const int row = m0 + wm * 32 + mi * 16 + kg * 4 + j;
                atomicAdd(ss_out + row, t);
            }
        }
}

// ================= final proj: xr = r[row] * (hb @ (W.gamma)^T) =================
__global__ __launch_bounds__(256) void projf_k(
    const short* __restrict__ A, const short* __restrict__ W,
    const float* __restrict__ ss_in, float* __restrict__ xr)
{
    __shared__ short As[2 * 64 * 32];
    __shared__ short Bs[2 * 64 * 32];
    f32x4 acc[2][2] = {};
    const int m0 = blockIdx.y * 64, n0 = blockIdx.x * 64;
    gemm_core64(acc, A, 512, W, 512, 512, As, Bs, m0, n0);
    const int lane = threadIdx.x & 63, wave = threadIdx.x >> 6;
    const int wm = wave >> 1, wn = wave & 1, l15 = lane & 15, kg = lane >> 4;
#pragma unroll
    for (int mi = 0; mi < 2; mi++)
#pragma unroll
        for (int j = 0; j < 4; j++) {
            const int row = m0 + wm * 32 + mi * 16 + kg * 4 + j;
            const float r = rsqrtf(ss_in[row] * (1.f / 512.f) + 1e-5f);
#pragma unroll
            for (int ni = 0; ni < 2; ni++) {
                const int col = n0 + wn * 32 + ni * 16 + l15;
                xr[(size_t)row * 2048 + col] = acc[mi][ni][j] * r;
            }
        }
}

// ================= coeffs + preds =================
__global__ __launch_bounds__(256) void coeffs_k(
    const float* __restrict__ outp, const float* __restrict__ inp,
    float* __restrict__ coeffs, float* __restrict__ preds)
{
    const int m = blockIdx.x;
    const int b = m >> 6;
    const int tid = threadIdx.x, wave = tid >> 6, lane = tid & 63;
    __shared__ float4 Us[256], Vs[256];
    __shared__ float ins[256];
    __shared__ float4 tpart[4];
    Us[tid] = *(const float4*)(outp + (size_t)m * 2048 + tid * 4);
    Vs[tid] = *(const float4*)(outp + (size_t)m * 2048 + 1024 + tid * 4);
    ins[tid] = inp[(size_t)m * 256 + tid];
    __syncthreads();
    const float4 vq0 = Vs[lane * 4 + 0], vq1 = Vs[lane * 4 + 1];
    const float4 vq2 = Vs[lane * 4 + 2], vq3 = Vs[lane * 4 + 3];
    float* cbase = coeffs + (size_t)m * 65536 + lane * 4;
#pragma unroll 4
    for (int i = 0; i < 64; i++) {
        const int pp = (wave << 6) + i;
        const float4 up = Us[pp];
        float4 c;
        c.x = up.x * vq0.x + up.y * vq0.y + up.z * vq0.z + up.w * vq0.w;
        c.y = up.x * vq1.x + up.y * vq1.y + up.z * vq1.z + up.w * vq1.w;
        c.z = up.x * vq2.x + up.y * vq2.y + up.z * vq2.z + up.w * vq2.w;
        c.w = up.x * vq3.x + up.y * vq3.y + up.z * vq3.z + up.w * vq3.w;
        *(float4*)(cbase + (size_t)pp * 256) = c;
    }
    const float iv = ins[tid];
    const float4 vm = Vs[tid];
    float4 t = make_float4(vm.x * iv, vm.y * iv, vm.z * iv, vm.w * iv);
#pragma unroll
    for (int off = 32; off > 0; off >>= 1) {
        t.x += __shfl_xor(t.x, off, 64);
        t.y += __shfl_xor(t.y, off, 64);
        t.z += __shfl_xor(t.z, off, 64);
        t.w += __shfl_xor(t.w, off, 64);
    }
    if (lane == 0) tpart[wave] = t;
    __syncthreads();
    const float4 t0 = tpart[0], t1 = tpart[1], t2 = tpart[2], t3 = tpart[3];
    const float4 tt = make_float4(t0.x + t1.x + t2.x + t3.x, t0.y + t1.y + t2.y + t3.y,
                                  t0.z + t1.z + t2.z + t3.z, t0.w + t1.w + t2.w + t3.w);
    const float4 up = Us[tid];
    const float pv = up.x * tt.x + up.y * tt.y + up.z * tt.z + up.w * tt.w;
    atomicAdd(preds + (size_t)b * 256 + tid, pv);
}

} // namespace

extern "C" void kernel_launch(void* const* d_in, const int* in_sizes, int n_in,
                              void* d_out, int out_size, void* d_ws, size_t ws_size,
                              hipStream_t stream)
{
    const float* inputs     = (const float*)d_in[0];
    const float* lin1_w     = (const float*)d_in[1];
    const float* lin1_b     = (const float*)d_in[2];
    const float* lin2_w     = (const float*)d_in[3];
    const float* lin2_b     = (const float*)d_in[4];
    const float* gate_w     = (const float*)d_in[5];
    const float* gate_b     = (const float*)d_in[6];
    const float* sp_norm_w  = (const float*)d_in[7];
    const float* in_proj_w  = (const float*)d_in[8];
    const float* conv_w     = (const float*)d_in[9];
    const float* conv_b     = (const float*)d_in[10];
    const float* x_proj_w   = (const float*)d_in[11];
    const float* dt_proj_w  = (const float*)d_in[12];
    const float* dt_proj_b  = (const float*)d_in[13];
    const float* A_log      = (const float*)d_in[14];
    const float* Dvec       = (const float*)d_in[15];
    const float* out_proj_w = (const float*)d_in[16];
    const float* blk_norm_w = (const float*)d_in[17];
    const float* post_norm_w= (const float*)d_in[18];
    const float* proj_w     = (const float*)d_in[19];

    float* ws = (float*)d_ws;
    // fp32 region
    float* h     = ws;                 // 1024 x 512
    float* xr    = ws + 524288;        // 1024 x 2048 (final proj out)
    float* x     = ws + 2621440;       // 1024 x 512 (lin2 out)
    float* g     = ws + 3145728;       // 1024 x 512
    float* ss    = ws + 3670016;       // 5 x 1024 sumsq slots
    // bf16 region
    short* bfb     = (short*)(ws + 3676160);
    short* inputsb = bfb;               // 1024 x 256
    short* h1b     = bfb + 262144;      // 1024 x 512
    short* hb      = bfb + 786432;      // 1024 x 512
    short* xcb     = bfb + 1310720;     // 1024 x 1024
    short* yb      = bfb + 2359296;     // 1024 x 1024
    short* srb     = bfb + 3407872;     // 1024 x 1024 silu(res)
    short* wlin1gb = bfb + 4456448;     // 1024 x 256
    short* wlin2b  = bfb + 4718592;     // 512 x 512
    short* winpb   = bfb + 4980736;     // 4 x 2048 x 512 (gamma-folded)
    short* woutpb  = bfb + 9175040;     // 4 x 512 x 1024
    short* wprojb  = bfb + 11272192;    // 2048 x 512 (gamma-folded)
    short* wxpdb   = bfb + 12320768;    // 4 x 1088 x 1024 ([xpw; W_delta])
    float* preds  = (float*)d_out;
    float* coeffs = (float*)d_out + 4096;

    const dim3 blk(256);

    prep_k<<<dim3(2080), blk, 0, stream>>>(
        lin1_w, gate_w, lin2_w, in_proj_w, out_proj_w, proj_w, x_proj_w, dt_proj_w,
        inputs, blk_norm_w, post_norm_w,
        wlin1gb, wlin2b, winpb, woutpb, wprojb, wxpdb, inputsb, preds, ss);

    lin1gate_k<<<dim3(16, 16), blk, 0, stream>>>(inputsb, wlin1gb, lin1_b, gate_b, h1b, g);
    lin2_k<<<dim3(8, 16), blk, 0, stream>>>(h1b, wlin2b, lin2_b, g, x);
    rms_sp_k<<<dim3(256), blk, 0, stream>>>(x, sp_norm_w, h, hb, ss);

    for (int l = 0; l < 4; l++) {
        inprojconv_k<<<dim3(32, 16), blk, 0, stream>>>(
            hb, winpb + (size_t)l * 1048576, ss + l * 1024,
            conv_w + (size_t)l * 4096, conv_b + l * 1024, xcb, srb);
        xpdscan_k<<<dim3(16, 16), blk, 0, stream>>>(
            xcb, wxpdb + (size_t)l * 1114112, dt_proj_b + l * 1024,
            A_log + (size_t)l * 16384, Dvec + l * 1024, srb, yb);
        outproj_k<<<dim3(8, 16), blk, 0, stream>>>(yb, woutpb + (size_t)l * 524288,
                                                   h, hb, ss + (l + 1) * 1024);
    }

    projf_k<<<dim3(32, 16), blk, 0, stream>>>(hb, wprojb, ss + 4096, xr);
    coeffs_k<<<dim3(1024), blk, 0, stream>>>(xr, inputs, coeffs, preds);
}